// Round 14
// baseline (204.574 us; speedup 1.0000x reference)
//
#include <hip/hip_runtime.h>
#include <hip/hip_fp16.h>

#define NN 50000
#define NG 256
#define CF 108
#define MD 88
#define OD 100
#define F2 44    // half2 per 88-feat row
#define HP 96    // h row stride in halfs (88 + 8 zero pad, MFMA K=96)
#define HP2 48   // h row stride in half2
#define HLS 104  // LDS h-tile row stride in halfs (208B -> conflict-free ds_read_b128)
#define YLS 96   // yl row stride in halfs (192B: rows span exactly 2x128B lines)
#define K1P 128  // layer-1 K padded (108 -> 128)
#define NSB 196      // super-buckets of 256 nodes
#define SBCAP 5120   // records per super-bucket (avg 4096)
#define TILE 2048    // edges per bin block
#define NCH 12       // 16B chunks per node in agg (11 real + 1 pad)

typedef _Float16 f16x8 __attribute__((ext_vector_type(8)));
typedef float f32x4 __attribute__((ext_vector_type(4)));

// ---------------- fused prep: binning | convx | weight transpose ----------------

__global__ __launch_bounds__(256) void prep_kernel(const int* __restrict__ edge, int E,
                                                   int* __restrict__ sbcur,
                                                   unsigned* __restrict__ sbrec,
                                                   const float* __restrict__ x,
                                                   _Float16* __restrict__ xh, int N,
                                                   const float* __restrict__ W1l, const float* __restrict__ W1r,
                                                   const float* __restrict__ W2l, const float* __restrict__ W2r,
                                                   const float* __restrict__ W3l, const float* __restrict__ W3r,
                                                   _Float16* __restrict__ Wct1, _Float16* __restrict__ Wct23,
                                                   int nbin, int nconvx) {
    const int tid = threadIdx.x;
    const int bb  = blockIdx.x;

    if (bb < nbin) {
        __shared__ int bcnt[NSB], boff[NSB], bfill[NSB], gbase[NSB];
        __shared__ int sc[256];
        __shared__ unsigned stag[TILE];
        __shared__ unsigned char stagbin[TILE];
        const int t0  = bb * TILE;
        const int tcnt = min(TILE, E - t0);

        for (int i = tid; i < NSB; i += 256) bcnt[i] = 0;
        __syncthreads();

        unsigned recs[TILE / 256];
        int      bins[TILE / 256];
        #pragma unroll
        for (int j = 0; j < TILE / 256; ++j) {
            const int e = t0 + j * 256 + tid;
            bins[j] = -1;
            if (e < E) {
                const int dst = edge[E + e], src = edge[e];
                bins[j] = dst >> 8;
                recs[j] = ((unsigned)src << 8) | (unsigned)(dst & 255);
                atomicAdd(&bcnt[bins[j]], 1);
            }
        }
        __syncthreads();

        sc[tid] = (tid < NSB) ? bcnt[tid] : 0;
        __syncthreads();
        for (int d = 1; d < 256; d <<= 1) {
            int v = (tid >= d) ? sc[tid - d] : 0;
            __syncthreads();
            sc[tid] += v;
            __syncthreads();
        }
        if (tid < NSB) {
            boff[tid]  = sc[tid] - bcnt[tid];
            bfill[tid] = sc[tid] - bcnt[tid];
            if (bcnt[tid] > 0) gbase[tid] = atomicAdd(&sbcur[tid], bcnt[tid]);
        }
        __syncthreads();

        #pragma unroll
        for (int j = 0; j < TILE / 256; ++j) {
            if (bins[j] >= 0) {
                int pos = atomicAdd(&bfill[bins[j]], 1);
                stag[pos]    = recs[j];
                stagbin[pos] = (unsigned char)bins[j];
            }
        }
        __syncthreads();

        for (int i = tid; i < tcnt; i += 256) {
            const int b   = stagbin[i];
            const int rel = i - boff[b];
            const int gp  = gbase[b] + rel;
            if (gp < SBCAP) sbrec[(size_t)b * SBCAP + gp] = stag[i];
        }
    } else if (bb < nbin + nconvx) {
        const int i = (bb - nbin) * 256 + tid;
        if (i < N * K1P) {
            int n = i >> 7, k = i & (K1P - 1);
            xh[i] = (k < CF) ? (_Float16)x[n * CF + k] : (_Float16)0.f;
        }
    } else {
        const int n1 = 176 * K1P;
        const int n2 = 176 * HP;
        const int idx = (bb - nbin - nconvx) * 256 + tid;
        if (idx < n1) {
            int c = idx / K1P, k = idx - c * K1P;
            float v = (k < CF) ? ((c < MD) ? W1l[k * MD + c] : W1r[k * MD + (c - MD)]) : 0.f;
            Wct1[idx] = (_Float16)v;
        } else if (idx < n1 + 2 * n2) {
            int j = idx - n1;
            const float* Wl = (j < n2) ? W2l : W3l;
            const float* Wr = (j < n2) ? W2r : W3r;
            int jj = (j < n2) ? j : j - n2;
            int c = jj / HP, k = jj - c * HP;
            float v = (k < MD) ? ((c < MD) ? Wl[k * MD + c] : Wr[k * MD + (c - MD)]) : 0.f;
            Wct23[j] = (_Float16)v;
        }
    }
}

// ---------------- per-super-bucket CSR + degree-sorted order (for standalone agg3) ----------

__global__ __launch_bounds__(256) void csr256_kernel(const unsigned* __restrict__ sbrec,
                                                     const int* __restrict__ sbcur,
                                                     int* __restrict__ csr,
                                                     int2* __restrict__ off2,
                                                     int* __restrict__ order, int N) {
    __shared__ int hist[256], base[256], offc[256], sc[256];
    __shared__ int dcnt[64], dpos[64];
    const int b = blockIdx.x, tid = threadIdx.x;
    const int cnt = min(sbcur[b], SBCAP);
    const unsigned* rec = sbrec + (size_t)b * SBCAP;

    hist[tid] = 0;
    if (tid < 64) dcnt[tid] = 0;
    __syncthreads();
    for (int r = tid; r < cnt; r += 256) atomicAdd(&hist[rec[r] & 255u], 1);
    __syncthreads();

    sc[tid] = hist[tid];
    __syncthreads();
    for (int d = 1; d < 256; d <<= 1) {
        int v = (tid >= d) ? sc[tid - d] : 0;
        __syncthreads();
        sc[tid] += v;
        __syncthreads();
    }
    base[tid] = sc[tid] - hist[tid];
    offc[tid] = base[tid];
    __syncthreads();

    for (int r = tid; r < cnt; r += 256) {
        const unsigned u = rec[r];
        const int dl = (int)(u & 255u);
        const int pos = atomicAdd(&offc[dl], 1);
        csr[(size_t)b * SBCAP + pos] = (int)(u >> 8);
    }

    const int n = b * 256 + tid;
    const int deg = (n < N) ? min(hist[tid], 63) : 63;
    atomicAdd(&dcnt[deg], 1);
    __syncthreads();
    if (tid < 64) {
        int v = dcnt[tid];
        int incl = v;
        #pragma unroll
        for (int s = 1; s < 64; s <<= 1) {
            int t = __shfl_up(incl, s, 64);
            if (tid >= s) incl += t;
        }
        dpos[tid] = incl - v;
    }
    __syncthreads();
    const int rank = atomicAdd(&dpos[deg], 1);
    order[b * 256 + rank] = (n < N) ? n : -1;

    if (n < N) off2[n] = make_int2(b * SBCAP + base[tid], hist[tid]);
}

// ---------------- gather helper: mean of neighbors + yr + relu, one 16B chunk ----------------

__device__ __forceinline__ f16x8 agg_chunk(const _Float16* __restrict__ yl,
                                           const _Float16* __restrict__ yr,
                                           int2 o, int n, size_t cof,
                                           const int* __restrict__ csr) {
    const int s = o.x, e = o.x + o.y;
    float a0[8] = {0,0,0,0,0,0,0,0}, a1[8] = {0,0,0,0,0,0,0,0};
    float a2[8] = {0,0,0,0,0,0,0,0}, a3[8] = {0,0,0,0,0,0,0,0};
    int i = s;
    for (; i + 7 < e; i += 8) {
        f16x8 v0 = *(const f16x8*)(yl + (size_t)csr[i]     * YLS + cof);
        f16x8 v1 = *(const f16x8*)(yl + (size_t)csr[i + 1] * YLS + cof);
        f16x8 v2 = *(const f16x8*)(yl + (size_t)csr[i + 2] * YLS + cof);
        f16x8 v3 = *(const f16x8*)(yl + (size_t)csr[i + 3] * YLS + cof);
        f16x8 v4 = *(const f16x8*)(yl + (size_t)csr[i + 4] * YLS + cof);
        f16x8 v5 = *(const f16x8*)(yl + (size_t)csr[i + 5] * YLS + cof);
        f16x8 v6 = *(const f16x8*)(yl + (size_t)csr[i + 6] * YLS + cof);
        f16x8 v7 = *(const f16x8*)(yl + (size_t)csr[i + 7] * YLS + cof);
        #pragma unroll
        for (int j = 0; j < 8; ++j) {
            a0[j] += (float)v0[j] + (float)v1[j];
            a1[j] += (float)v2[j] + (float)v3[j];
            a2[j] += (float)v4[j] + (float)v5[j];
            a3[j] += (float)v6[j] + (float)v7[j];
        }
    }
    for (; i + 1 < e; i += 2) {
        f16x8 v0 = *(const f16x8*)(yl + (size_t)csr[i]     * YLS + cof);
        f16x8 v1 = *(const f16x8*)(yl + (size_t)csr[i + 1] * YLS + cof);
        #pragma unroll
        for (int j = 0; j < 8; ++j) { a0[j] += (float)v0[j]; a1[j] += (float)v1[j]; }
    }
    if (i < e) {
        f16x8 v0 = *(const f16x8*)(yl + (size_t)csr[i] * YLS + cof);
        #pragma unroll
        for (int j = 0; j < 8; ++j) a0[j] += (float)v0[j];
    }
    const float inv = 1.0f / (float)max(o.y, 1);
    const f16x8 r = *(const f16x8*)(yr + (size_t)n * MD + cof);
    f16x8 outv;
    #pragma unroll
    for (int j = 0; j < 8; ++j) {
        float v = (a0[j] + a1[j] + a2[j] + a3[j]) * inv + (float)r[j];
        outv[j] = (_Float16)fmaxf(v, 0.f);
    }
    return outv;
}

// ---------------- fused agg + MFMA gemm: block owns 128 nodes ----------------
// Phase A: aggregate layer-l output (yl_in/yr_in) for these nodes -> LDS h-tile.
// Phase B: y_{l+1} = h @ Wct^T (+bias) from LDS A-fragments -> yl_out/yr_out.

__global__ __launch_bounds__(256) void agg_gemm_kernel(const _Float16* __restrict__ yl_in,
                                                       const _Float16* __restrict__ yr_in,
                                                       const int2* __restrict__ off2,
                                                       const int* __restrict__ csr,
                                                       const _Float16* __restrict__ Wct,
                                                       const float* __restrict__ bias,
                                                       _Float16* __restrict__ yl_out,
                                                       _Float16* __restrict__ yr_out, int N) {
    __shared__ _Float16 hl[128 * HLS];   // 26 KiB
    const int tid = threadIdx.x;
    const int nb0 = blockIdx.x * 128;

    // ---- Phase A: 128 nodes x 12 chunks = 1536 items
    #pragma unroll
    for (int k = 0; k < 6; ++k) {
        const int item = k * 256 + tid;
        const int node = item / NCH;
        const int c = item - node * NCH;
        const int n = nb0 + node;
        if (c >= 11 || n >= N) {
            const int off = (c >= 11) ? 88 : c * 8;
            *(f16x8*)(hl + (size_t)node * HLS + off) = (f16x8)(_Float16)0.f;
            continue;
        }
        const size_t cof = (size_t)c * 8;
        f16x8 outv = agg_chunk(yl_in, yr_in, off2[n], n, cof, csr);
        *(f16x8*)(hl + (size_t)node * HLS + cof) = outv;
    }
    __syncthreads();

    // ---- Phase B: MFMA, A from LDS
    const int wave = tid >> 6;
    const int lane = tid & 63;
    const int r16  = lane & 15;
    const int kg   = lane >> 4;
    const int rbase = nb0 + wave * 16;

    const _Float16* ap0 = hl + (size_t)(wave * 16 + r16) * HLS + kg * 8;
    const _Float16* ap1 = hl + (size_t)(wave * 16 + 64 + r16) * HLS + kg * 8;

    f32x4 acc[2][11];
    #pragma unroll
    for (int q = 0; q < 2; ++q)
        #pragma unroll
        for (int t = 0; t < 11; ++t) acc[q][t] = (f32x4){0.f, 0.f, 0.f, 0.f};

    #pragma unroll
    for (int ks = 0; ks < HP / 32; ++ks) {
        f16x8 af0 = *(const f16x8*)(ap0 + ks * 32);
        f16x8 af1 = *(const f16x8*)(ap1 + ks * 32);
        #pragma unroll
        for (int t = 0; t < 11; ++t) {
            const _Float16* bp = Wct + (size_t)(t * 16 + r16) * HP + ks * 32 + kg * 8;
            f16x8 bf = *(const f16x8*)bp;
            acc[0][t] = __builtin_amdgcn_mfma_f32_16x16x32_f16(af0, bf, acc[0][t], 0, 0, 0);
            acc[1][t] = __builtin_amdgcn_mfma_f32_16x16x32_f16(af1, bf, acc[1][t], 0, 0, 0);
        }
    }

    #pragma unroll
    for (int q = 0; q < 2; ++q) {
        const int orow0 = rbase + q * 64 + kg * 4;
        #pragma unroll
        for (int t = 0; t < 11; ++t) {
            const int c = t * 16 + r16;
            const bool isr = (c >= MD);
            const float bv = isr ? bias[c - MD] : 0.f;
            _Float16* dst = isr ? (yr_out + (c - MD)) : (yl_out + c);
            const int st = isr ? MD : YLS;
            #pragma unroll
            for (int r = 0; r < 4; ++r) {
                const int row = orow0 + r;
                if (row < N) dst[(size_t)row * st] = (_Float16)(acc[q][t][r] + bv);
            }
        }
    }
}

// ---------------- MFMA GEMM (layer 1, global A) ----------------

template <int KPAD>
__global__ __launch_bounds__(256) void gemm_mfma_kernel(const _Float16* __restrict__ Ah,
                                                        const _Float16* __restrict__ Wct,
                                                        const float* __restrict__ bias,
                                                        _Float16* __restrict__ yl,
                                                        _Float16* __restrict__ yr, int N) {
    const int wave = threadIdx.x >> 6;
    const int lane = threadIdx.x & 63;
    const int r16  = lane & 15;
    const int kg   = lane >> 4;
    const int rbase = blockIdx.x * 128 + wave * 16;

    const int arow0 = min(rbase + r16, N - 1);
    const int arow1 = min(rbase + 64 + r16, N - 1);
    const _Float16* ap0 = Ah + (size_t)arow0 * KPAD + kg * 8;
    const _Float16* ap1 = Ah + (size_t)arow1 * KPAD + kg * 8;

    f32x4 acc[2][11];
    #pragma unroll
    for (int q = 0; q < 2; ++q)
        #pragma unroll
        for (int t = 0; t < 11; ++t) acc[q][t] = (f32x4){0.f, 0.f, 0.f, 0.f};

    #pragma unroll
    for (int ks = 0; ks < KPAD / 32; ++ks) {
        f16x8 af0 = *(const f16x8*)(ap0 + ks * 32);
        f16x8 af1 = *(const f16x8*)(ap1 + ks * 32);
        #pragma unroll
        for (int t = 0; t < 11; ++t) {
            const _Float16* bp = Wct + (size_t)(t * 16 + r16) * KPAD + ks * 32 + kg * 8;
            f16x8 bf = *(const f16x8*)bp;
            acc[0][t] = __builtin_amdgcn_mfma_f32_16x16x32_f16(af0, bf, acc[0][t], 0, 0, 0);
            acc[1][t] = __builtin_amdgcn_mfma_f32_16x16x32_f16(af1, bf, acc[1][t], 0, 0, 0);
        }
    }

    #pragma unroll
    for (int q = 0; q < 2; ++q) {
        const int orow0 = rbase + q * 64 + kg * 4;
        #pragma unroll
        for (int t = 0; t < 11; ++t) {
            const int c = t * 16 + r16;
            const bool isr = (c >= MD);
            const float bv = isr ? bias[c - MD] : 0.f;
            _Float16* dst = isr ? (yr + (c - MD)) : (yl + c);
            const int st = isr ? MD : YLS;
            #pragma unroll
            for (int r = 0; r < 4; ++r) {
                const int row = orow0 + r;
                if (row < N) dst[(size_t)row * st] = (_Float16)(acc[q][t][r] + bv);
            }
        }
    }
}

// ---------------- standalone aggregate (layer 3): deg-sorted, writes h ----------------

__global__ void agg_kernel(const _Float16* __restrict__ yl, const _Float16* __restrict__ yr,
                           const int2* __restrict__ off2, const int* __restrict__ csr,
                           const int* __restrict__ order,
                           _Float16* __restrict__ h, int total) {
    int idx = blockIdx.x * blockDim.x + threadIdx.x;
    if (idx >= total) return;
    int slot = idx / NCH;
    int c = idx - slot * NCH;
    const int n = order[slot];
    if (n < 0) return;
    if (c >= 11) {
        *(f16x8*)(h + (size_t)n * HP + 88) = (f16x8)(_Float16)0.f;
        return;
    }
    const size_t cof = (size_t)c * 8;
    f16x8 outv = agg_chunk(yl, yr, off2[n], n, cof, csr);
    *(f16x8*)(h + (size_t)n * HP + cof) = outv;
}

// ---------------- fused pool + classifier: block per graph ----------------

__global__ __launch_bounds__(256) void pool_final_kernel(const __half2* __restrict__ h2,
                                                         const int* __restrict__ batch,
                                                         const float* __restrict__ Wlin,
                                                         const float* __restrict__ blin,
                                                         float* __restrict__ out, int N) {
    __shared__ float red[4][F2][2];
    __shared__ float pooled[MD];
    __shared__ int range[2];
    const int g    = blockIdx.x;
    const int tid  = threadIdx.x;
    const int w    = tid >> 6;
    const int lane = tid & 63;

    if (tid < 2) {
        const int tgt = g + tid;
        int lo = 0, hi = N;
        while (lo < hi) {
            int mid = (lo + hi) >> 1;
            if (batch[mid] < tgt) lo = mid + 1; else hi = mid;
        }
        range[tid] = lo;
    }
    __syncthreads();
    const int s = range[0], e = range[1];

    float ax0 = 0.f, ay0 = 0.f, ax1 = 0.f, ay1 = 0.f;
    if (lane < F2) {
        int n = s + w;
        for (; n + 4 < e; n += 8) {
            __half2 v0 = h2[(size_t)n * HP2 + lane];
            __half2 v1 = h2[(size_t)(n + 4) * HP2 + lane];
            ax0 += __low2float(v0); ay0 += __high2float(v0);
            ax1 += __low2float(v1); ay1 += __high2float(v1);
        }
        if (n < e) {
            __half2 v0 = h2[(size_t)n * HP2 + lane];
            ax0 += __low2float(v0); ay0 += __high2float(v0);
        }
        red[w][lane][0] = ax0 + ax1;
        red[w][lane][1] = ay0 + ay1;
    }
    __syncthreads();
    if (tid < F2) {
        pooled[2 * tid]     = red[0][tid][0] + red[1][tid][0] + red[2][tid][0] + red[3][tid][0];
        pooled[2 * tid + 1] = red[0][tid][1] + red[1][tid][1] + red[2][tid][1] + red[3][tid][1];
    }
    __syncthreads();
    if (tid < OD) {
        float acc = blin[tid];
        #pragma unroll 8
        for (int f = 0; f < MD; ++f)
            acc = fmaf(pooled[f], Wlin[f * OD + tid], acc);
        out[(size_t)g * OD + tid] = acc;
    }
}

// ---------------- launch ----------------

extern "C" void kernel_launch(void* const* d_in, const int* in_sizes, int n_in,
                              void* d_out, int out_size, void* d_ws, size_t ws_size,
                              hipStream_t stream) {
    const float* x     = (const float*)d_in[0];
    const int*   edge  = (const int*)d_in[1];
    const int*   batch = (const int*)d_in[2];
    const float* W1l = (const float*)d_in[3];
    const float* W1r = (const float*)d_in[4];
    const float* b1  = (const float*)d_in[5];
    const float* W2l = (const float*)d_in[6];
    const float* W2r = (const float*)d_in[7];
    const float* b2  = (const float*)d_in[8];
    const float* W3l = (const float*)d_in[9];
    const float* W3r = (const float*)d_in[10];
    const float* b3  = (const float*)d_in[11];
    const float* Wlin = (const float*)d_in[12];
    const float* blin = (const float*)d_in[13];
    float* out = (float*)d_out;

    const int N = in_sizes[0] / CF;     // 50000
    const int E = in_sizes[1] / 2;      // 800000

    char* ws = (char*)d_ws;
    auto alloc = [&](size_t bytes) -> void* {
        void* p = (void*)ws;
        ws += (bytes + 255) & ~(size_t)255;
        return p;
    };
    int*       sbcur   = (int*)alloc((size_t)NSB * 4);
    unsigned*  sbrec   = (unsigned*)alloc((size_t)NSB * SBCAP * 4);
    int*       csr     = (int*)alloc((size_t)NSB * SBCAP * 4);
    int2*      off2    = (int2*)alloc((size_t)N * 8);
    int*       order   = (int*)alloc((size_t)NSB * 256 * 4);
    _Float16*  Wct1    = (_Float16*)alloc((size_t)176 * K1P * 2);
    _Float16*  Wct23   = (_Float16*)alloc((size_t)2 * 176 * HP * 2);
    _Float16*  xh      = (_Float16*)alloc((size_t)N * K1P * 2);
    _Float16*  ylA     = (_Float16*)alloc((size_t)N * YLS * 2);
    _Float16*  yrA     = (_Float16*)alloc((size_t)N * MD * 2);
    _Float16*  ylB     = (_Float16*)alloc((size_t)N * YLS * 2);
    _Float16*  yrB     = (_Float16*)alloc((size_t)N * MD * 2);
    _Float16*  h       = (_Float16*)alloc((size_t)N * HP * 2);

    const int nbin   = (E + TILE - 1) / TILE;
    const int nconvx = (N * K1P + 255) / 256;
    const int nwct   = (176 * K1P + 2 * 176 * HP + 255) / 256;

    hipMemsetAsync(sbcur, 0, (size_t)NSB * 4, stream);
    prep_kernel<<<nbin + nconvx + nwct, 256, 0, stream>>>(
        edge, E, sbcur, sbrec, x, xh, N,
        W1l, W1r, W2l, W2r, W3l, W3r, Wct1, Wct23, nbin, nconvx);
    csr256_kernel<<<NSB, 256, 0, stream>>>(sbrec, sbcur, csr, off2, order, N);

    const int row_blocks = (N + 127) / 128;
    const int agg_total  = NSB * 256 * NCH;
    const int agg_blocks = (agg_total + 255) / 256;

    // layer 1: y1 = gemm(xh)
    gemm_mfma_kernel<K1P><<<row_blocks, 256, 0, stream>>>(xh, Wct1, b1, ylA, yrA, N);
    // layer 2 fused: h1 = agg(y1); y2 = gemm(h1)
    agg_gemm_kernel<<<row_blocks, 256, 0, stream>>>(ylA, yrA, off2, csr, Wct23, b2, ylB, yrB, N);
    // layer 3 fused: h2 = agg(y2); y3 = gemm(h2)
    agg_gemm_kernel<<<row_blocks, 256, 0, stream>>>(ylB, yrB, off2, csr,
                                                    Wct23 + (size_t)176 * HP, b3, ylA, yrA, N);
    // h3 = agg(y3)
    agg_kernel<<<agg_blocks, 256, 0, stream>>>(ylA, yrA, off2, csr, order, h, agg_total);
    // pooled + classifier
    pool_final_kernel<<<NG, 256, 0, stream>>>((const __half2*)h, batch, Wlin, blin, out, N);
}